// Round 1
// baseline (465.044 us; speedup 1.0000x reference)
//
#include <hip/hip_runtime.h>

typedef unsigned short u16;
typedef short v8s __attribute__((ext_vector_type(8)));
typedef float v4f __attribute__((ext_vector_type(4)));
typedef u16  v4u __attribute__((ext_vector_type(4)));

__device__ __forceinline__ float bf2f(u16 h){ return __uint_as_float(((unsigned)h)<<16); }
__device__ __forceinline__ u16 f2bf(float f){
  unsigned u = __float_as_uint(f);
  u += 0x7FFFu + ((u>>16)&1u);
  return (u16)(u>>16);
}
__device__ __forceinline__ float siluf(float x){ return x/(1.f+__expf(-x)); }
__device__ __forceinline__ float softplusf(float x){
  return (x>15.f) ? x : __logf(1.f+__expf(x));
}

// ---------------------------------------------------------------------------
// Weight f32 -> bf16 conversion (runs every call; ws is re-poisoned each call)
// segments: W_inproj 6291456 | W_xproj 589824 | W_dt 196608 | W_outproj 3145728
// ---------------------------------------------------------------------------
__global__ __launch_bounds__(256) void cvt_kernel(
  const float* __restrict__ s0, const float* __restrict__ s1,
  const float* __restrict__ s2, const float* __restrict__ s3,
  u16* __restrict__ d0, u16* __restrict__ d1,
  u16* __restrict__ d2, u16* __restrict__ d3)
{
  const int c0=6291456, c1=c0+589824, c2=c1+196608, c3=c2+3145728;
  int i4 = (blockIdx.x*256 + threadIdx.x)*4;
  if(i4 >= c3) return;
  const float* src; u16* dst; int off;
  if(i4 < c0){ src=s0; dst=d0; off=i4; }
  else if(i4 < c1){ src=s1; dst=d1; off=i4-c0; }
  else if(i4 < c2){ src=s2; dst=d2; off=i4-c1; }
  else           { src=s3; dst=d3; off=i4-c2; }
  float4 v = *(const float4*)(src+off);
  v4u o = { f2bf(v.x), f2bf(v.y), f2bf(v.z), f2bf(v.w) };
  *(v4u*)(dst+off) = o;
}

// ---------------------------------------------------------------------------
// Input MLP: h[b,d] = relu(sum_f x[b,4+f]*w_in[d,f] + b_in[d]),  (1024,512) f32
// ---------------------------------------------------------------------------
__global__ __launch_bounds__(256) void input_kernel(
  const float* __restrict__ x, const float* __restrict__ w,
  const float* __restrict__ bi, float* __restrict__ h)
{
  int idx = blockIdx.x*256 + threadIdx.x;
  int b = idx >> 9, d = idx & 511;
  const float* xr = x + b*68 + 4;
  const float* wr = w + d*64;
  float a = bi[d];
#pragma unroll
  for(int f=0; f<64; f++) a += xr[f]*wr[f];
  h[idx] = fmaxf(a, 0.f);
}

// ---------------------------------------------------------------------------
// LayerNorm over 512, output bf16. One block per row.
// ---------------------------------------------------------------------------
__global__ __launch_bounds__(256) void ln_kernel(
  const float* __restrict__ h, const float* __restrict__ g,
  const float* __restrict__ bta, u16* __restrict__ hn)
{
  int row = blockIdx.x;
  int t = threadIdx.x;
  float v0 = h[row*512 + t], v1 = h[row*512 + 256 + t];
  float s = v0+v1, s2 = v0*v0 + v1*v1;
#pragma unroll
  for(int off=32; off; off>>=1){ s += __shfl_down(s, off); s2 += __shfl_down(s2, off); }
  __shared__ float red[8];
  int wid = t>>6;
  if((t&63)==0){ red[wid*2]=s; red[wid*2+1]=s2; }
  __syncthreads();
  float mu = (red[0]+red[2]+red[4]+red[6]) * (1.f/512.f);
  float ms = (red[1]+red[3]+red[5]+red[7]) * (1.f/512.f);
  float rstd = rsqrtf(ms - mu*mu + 1e-5f);
  hn[row*512+t]     = f2bf((v0-mu)*rstd*g[t]     + bta[t]);
  hn[row*512+256+t] = f2bf((v1-mu)*rstd*g[t+256] + bta[t+256]);
}

// ---------------------------------------------------------------------------
// s[b] = dot(Bm,Cm) over 32 states; also extract dt (first 32 cols) as bf16.
// 8 lanes per row, 32 rows per block.
// ---------------------------------------------------------------------------
__global__ __launch_bounds__(256) void sdt_kernel(
  const float* __restrict__ xd, u16* __restrict__ dtb, float* __restrict__ sb)
{
  int t = threadIdx.x;
  int row = blockIdx.x*32 + (t>>3);
  int sub = t&7;
  const float* xr = xd + row*96;
  float a = 0.f;
#pragma unroll
  for(int i=0;i<4;i++){ int n = sub + 8*i; a += xr[32+n]*xr[64+n]; }
  a += __shfl_xor(a,1); a += __shfl_xor(a,2); a += __shfl_xor(a,4);
  if(sub==0) sb[row] = a;
#pragma unroll
  for(int i=0;i<4;i++){ int r = sub + 8*i; dtb[row*32+r] = f2bf(xr[r]); }
}

// ---------------------------------------------------------------------------
// Generic bf16 MFMA GEMM: C[m,n] = sum_k A[m,k]*B[n,k]  (B stored N x K, i.e. W row-major)
// MODE 0: GEMM1  -> u = silu(xc*cw3+cb) [n<1536], zs = silu(z) [n>=1536]
// MODE 1: GEMM2  -> split-K atomic f32 add into x_dbl (1024x96)
// MODE 2: GEMM3  -> delta=softplus(acc+bdt); y = u*(delta*s + Dp)*zs  (bf16)
// MODE 3: GEMM4  -> h += acc (f32 residual)
// mfma_f32_16x16x32_bf16 layouts (learn_hip m89/m91/m97 verified):
//   A/B frag: lane holds [idx=lane&15][k=(lane>>4)*8 + j], 8 contiguous-K bf16
//   C/D: col=lane&15, row=(lane>>4)*4+reg
// ---------------------------------------------------------------------------
template<int BM,int BN,int WM,int WN,int MODE>
__global__ __launch_bounds__(256)
void gemm_mfma(const u16* __restrict__ A, int lda,
               const u16* __restrict__ B, int ldb, int Klen,
               const float* __restrict__ p0, const float* __restrict__ p1,
               const float* __restrict__ p2,
               const u16* __restrict__ q0, const u16* __restrict__ q1,
               u16* __restrict__ o16a, u16* __restrict__ o16b,
               float* __restrict__ o32)
{
  constexpr int MI = WM/16, NI = WN/16;
  constexpr int WCOLS = BN/WN;
  constexpr int LDSK = 40;               // 32 + 8 pad: only 2-way bank alias (free)
  static_assert((BM/WM)*(BN/WN) == 4, "4 waves");
  __shared__ u16 As[BM*LDSK];
  __shared__ u16 Bs[BN*LDSK];
  const int tid  = threadIdx.x;
  const int lane = tid & 63, wid = tid >> 6;
  const int wm = wid / WCOLS, wn = wid % WCOLS;
  const int m0 = blockIdx.y*BM, n0 = blockIdx.x*BN;
  const int k0 = blockIdx.z*Klen;
  const int qd = lane>>4, lr = lane&15;

  v4f acc[MI][NI];
#pragma unroll
  for(int i=0;i<MI;i++)
#pragma unroll
    for(int j=0;j<NI;j++) acc[i][j] = v4f{0.f,0.f,0.f,0.f};

  for(int kk=0; kk<Klen; kk+=32){
    __syncthreads();
    for(int idx=tid; idx < BM*4; idx += 256){
      int r = idx>>2, sg = idx&3;
      *(v8s*)(As + r*LDSK + sg*8) = *(const v8s*)(A + (size_t)(m0+r)*lda + (k0+kk) + sg*8);
    }
    for(int idx=tid; idx < BN*4; idx += 256){
      int r = idx>>2, sg = idx&3;
      *(v8s*)(Bs + r*LDSK + sg*8) = *(const v8s*)(B + (size_t)(n0+r)*ldb + (k0+kk) + sg*8);
    }
    __syncthreads();
    v8s af[MI], bfv[NI];
#pragma unroll
    for(int i=0;i<MI;i++) af[i]  = *(const v8s*)(As + (wm*WM + i*16 + lr)*LDSK + qd*8);
#pragma unroll
    for(int j=0;j<NI;j++) bfv[j] = *(const v8s*)(Bs + (wn*WN + j*16 + lr)*LDSK + qd*8);
#pragma unroll
    for(int i=0;i<MI;i++)
#pragma unroll
      for(int j=0;j<NI;j++)
        acc[i][j] = __builtin_amdgcn_mfma_f32_16x16x32_bf16(af[i], bfv[j], acc[i][j], 0,0,0);
  }

#pragma unroll
  for(int i=0;i<MI;i++)
#pragma unroll
    for(int j=0;j<NI;j++){
      const int gb0 = m0 + wm*WM + i*16 + qd*4;
      const int ge  = n0 + wn*WN + j*16 + lr;
#pragma unroll
      for(int r=0;r<4;r++){
        const int gb = gb0 + r;
        float val = acc[i][j][r];
        if constexpr (MODE==0){
          if(ge < 1536){
            float t = val * p0[ge*4+3] + p1[ge];      // conv last tap + bias
            o16a[(size_t)gb*1536 + ge] = f2bf(siluf(t));
          } else {
            o16b[(size_t)gb*1536 + (ge-1536)] = f2bf(siluf(val));
          }
        } else if constexpr (MODE==1){
          atomicAdd(o32 + (size_t)gb*96 + ge, val);
        } else if constexpr (MODE==2){
          float delta = softplusf(val + p0[ge]);
          float uu = bf2f(q0[(size_t)gb*1536+ge]);
          float zz = bf2f(q1[(size_t)gb*1536+ge]);
          o16a[(size_t)gb*1536+ge] = f2bf(uu*(delta*p2[gb] + p1[ge])*zz);
        } else {
          o32[(size_t)gb*512 + ge] += val;
        }
      }
    }
}

// ---------------------------------------------------------------------------
// Head: lg=sigmoid(rain.wlog+b); gate=lg*Wg+bg; fused=m*gate;
// z1=relu(fused@Wh1^T+bh1); out=sigmoid(z1@Wh2^T+bh2). One block per row.
// ---------------------------------------------------------------------------
__global__ __launch_bounds__(256) void head_kernel(
  const float* __restrict__ x, const float* __restrict__ h,
  const float* __restrict__ wlog, const float* __restrict__ blog,
  const float* __restrict__ wg, const float* __restrict__ bg,
  const float* __restrict__ wh1, const float* __restrict__ bh1,
  const float* __restrict__ wh2, const float* __restrict__ bh2,
  float* __restrict__ out)
{
  int b = blockIdx.x, t = threadIdx.x;
  __shared__ float fused[512];
  __shared__ float part[256];
  __shared__ float z1s[32];
  float lgin = x[b*68+0]*wlog[0] + x[b*68+1]*wlog[1]
             + x[b*68+2]*wlog[2] + x[b*68+3]*wlog[3] + blog[0];
  float lg = 1.f/(1.f+__expf(-lgin));
  for(int d=t; d<512; d+=256){
    fused[d] = h[(size_t)b*512+d]*(lg*wg[d] + bg[d]);
  }
  __syncthreads();
  int j = t&31, c = t>>5;
  float p = 0.f;
#pragma unroll
  for(int i=0;i<64;i++){ int d = c*64+i; p += fused[d]*wh1[j*512+d]; }
  part[t] = p;
  __syncthreads();
  if(t < 32){
    float z = bh1[t];
#pragma unroll
    for(int cc=0; cc<8; cc++) z += part[cc*32+t];
    z1s[t] = fmaxf(z, 0.f);
  }
  __syncthreads();
  if(t==0){
    float lo = bh2[0];
#pragma unroll
    for(int jj=0;jj<32;jj++) lo += z1s[jj]*wh2[jj];
    out[b] = 1.f/(1.f+__expf(-lo));
  }
}

// ---------------------------------------------------------------------------
extern "C" void kernel_launch(void* const* d_in, const int* in_sizes, int n_in,
                              void* d_out, int out_size, void* d_ws, size_t ws_size,
                              hipStream_t stream)
{
  const float* x        = (const float*)d_in[0];
  const float* w_in     = (const float*)d_in[1];
  const float* b_in     = (const float*)d_in[2];
  const float* ln_g     = (const float*)d_in[3];
  const float* ln_b     = (const float*)d_in[4];
  const float* W_inproj = (const float*)d_in[5];
  const float* conv_w   = (const float*)d_in[6];
  const float* conv_b   = (const float*)d_in[7];
  const float* W_xproj  = (const float*)d_in[8];
  const float* W_dt     = (const float*)d_in[9];
  const float* b_dt     = (const float*)d_in[10];
  // d_in[11] A_log: provably dead — scan starts at h0=0, dA only multiplies h0
  const float* D_skip   = (const float*)d_in[12];
  const float* W_outproj= (const float*)d_in[13];
  const float* w_log    = (const float*)d_in[14];
  const float* b_log    = (const float*)d_in[15];
  const float* W_gate   = (const float*)d_in[16];
  const float* b_gate   = (const float*)d_in[17];
  const float* W_h1     = (const float*)d_in[18];
  const float* b_h1     = (const float*)d_in[19];
  const float* W_h2     = (const float*)d_in[20];
  const float* b_h2     = (const float*)d_in[21];
  float* out = (float*)d_out;
  (void)in_sizes; (void)n_in; (void)out_size; (void)ws_size;

  char* ws = (char*)d_ws;
  size_t off = 0;
  auto alloc = [&](size_t bytes)->char*{
    char* p = ws + off; off = (off + bytes + 255) & ~(size_t)255; return p; };
  u16*   wInB  = (u16*)  alloc(6291456u*2);   // 4 x 3072 x 512
  u16*   wXB   = (u16*)  alloc(589824u*2);    // 4 x 96 x 1536
  u16*   wDtB  = (u16*)  alloc(196608u*2);    // 4 x 1536 x 32
  u16*   wOutB = (u16*)  alloc(3145728u*2);   // 4 x 512 x 1536
  float* h     = (float*)alloc(524288u*4);    // 1024 x 512 residual stream
  u16*   hn    = (u16*)  alloc(524288u*2);    // layernormed, bf16
  u16*   u     = (u16*)  alloc(1572864u*2);   // 1024 x 1536
  u16*   zs    = (u16*)  alloc(1572864u*2);   // silu(z)
  float* xdbl  = (float*)alloc(98304u*4);     // 1024 x 96
  u16*   dtb   = (u16*)  alloc(32768u*2);     // 1024 x 32
  float* sb    = (float*)alloc(1024u*4);      // s[b]
  u16*   y     = (u16*)  alloc(1572864u*2);   // 1024 x 1536

  cvt_kernel<<<9984,256,0,stream>>>(W_inproj, W_xproj, W_dt, W_outproj,
                                    wInB, wXB, wDtB, wOutB);
  input_kernel<<<2048,256,0,stream>>>(x, w_in, b_in, h);

  for(int l=0;l<4;l++){
    ln_kernel<<<1024,256,0,stream>>>(h, ln_g+l*512, ln_b+l*512, hn);
    // GEMM1: hn(1024x512) @ W_inproj^T -> u | zs   (N=3072, K=512)
    gemm_mfma<128,128,64,64,0><<<dim3(24,8,1),256,0,stream>>>(
      hn, 512, wInB+(size_t)l*1572864, 512, 512,
      conv_w+l*6144, conv_b+l*1536, nullptr, nullptr, nullptr, u, zs, nullptr);
    // GEMM2: u(1024x1536) @ W_xproj^T -> x_dbl (N=96), split-K=8 with atomics
    hipMemsetAsync(xdbl, 0, 98304u*4, stream);
    gemm_mfma<64,96,32,48,1><<<dim3(1,16,8),256,0,stream>>>(
      u, 1536, wXB+(size_t)l*147456, 1536, 192,
      nullptr, nullptr, nullptr, nullptr, nullptr, nullptr, nullptr, xdbl);
    sdt_kernel<<<32,256,0,stream>>>(xdbl, dtb, sb);
    // GEMM3: dt(1024x32) @ W_dt^T -> delta -> y   (N=1536, K=32)
    gemm_mfma<64,64,32,32,2><<<dim3(24,16,1),256,0,stream>>>(
      dtb, 32, wDtB+(size_t)l*49152, 32, 32,
      b_dt+l*1536, D_skip+l*1536, sb, u, zs, y, nullptr, nullptr);
    // GEMM4: y(1024x1536) @ W_outproj^T -> h += (N=512, K=1536)
    gemm_mfma<64,64,32,32,3><<<dim3(8,16,1),256,0,stream>>>(
      y, 1536, wOutB+(size_t)l*786432, 1536, 1536,
      nullptr, nullptr, nullptr, nullptr, nullptr, nullptr, nullptr, h);
  }

  head_kernel<<<1024,256,0,stream>>>(x, h, w_log, b_log, W_gate, b_gate,
                                     W_h1, b_h1, W_h2, b_h2, out);
}

// Round 2
// 323.861 us; speedup vs baseline: 1.4359x; 1.4359x over previous
//
#include <hip/hip_runtime.h>

typedef unsigned short u16;
typedef short v8s __attribute__((ext_vector_type(8)));
typedef float v4f __attribute__((ext_vector_type(4)));
typedef u16  v4u __attribute__((ext_vector_type(4)));

__device__ __forceinline__ float bf2f(u16 h){ return __uint_as_float(((unsigned)h)<<16); }
__device__ __forceinline__ u16 f2bf(float f){
  unsigned u = __float_as_uint(f);
  u += 0x7FFFu + ((u>>16)&1u);
  return (u16)(u>>16);
}
__device__ __forceinline__ float siluf(float x){ return x/(1.f+__expf(-x)); }
__device__ __forceinline__ float softplusf(float x){
  return (x>15.f) ? x : __logf(1.f+__expf(x));
}

// ---------------------------------------------------------------------------
// Weight f32 -> bf16 (ws re-poisoned each call, so this runs every call).
// This is also the single HBM read of the weights; GEMMs then hit L2/L3 bf16.
// ---------------------------------------------------------------------------
__global__ __launch_bounds__(256) void cvt_kernel(
  const float* __restrict__ s0, const float* __restrict__ s1,
  const float* __restrict__ s2, const float* __restrict__ s3,
  u16* __restrict__ d0, u16* __restrict__ d1,
  u16* __restrict__ d2, u16* __restrict__ d3)
{
  const int c0=6291456, c1=c0+589824, c2=c1+196608, c3=c2+3145728;
  int i4 = (blockIdx.x*256 + threadIdx.x)*4;
  if(i4 >= c3) return;
  const float* src; u16* dst; int off;
  if(i4 < c0){ src=s0; dst=d0; off=i4; }
  else if(i4 < c1){ src=s1; dst=d1; off=i4-c0; }
  else if(i4 < c2){ src=s2; dst=d2; off=i4-c1; }
  else           { src=s3; dst=d3; off=i4-c2; }
  float4 v = *(const float4*)(src+off);
  v4u o = { f2bf(v.x), f2bf(v.y), f2bf(v.z), f2bf(v.w) };
  *(v4u*)(dst+off) = o;
}

// ---------------------------------------------------------------------------
// Input MLP: h[b,d] = relu(sum_f x[b,4+f]*w_in[d,f] + b_in[d])
// ---------------------------------------------------------------------------
__global__ __launch_bounds__(256) void input_kernel(
  const float* __restrict__ x, const float* __restrict__ w,
  const float* __restrict__ bi, float* __restrict__ h)
{
  int idx = blockIdx.x*256 + threadIdx.x;
  int b = idx >> 9, d = idx & 511;
  const float* xr = x + b*68 + 4;
  const float* wr = w + d*64;
  float a = bi[d];
#pragma unroll
  for(int f=0; f<64; f++) a += xr[f]*wr[f];
  h[idx] = fmaxf(a, 0.f);
}

// ---------------------------------------------------------------------------
// LayerNorm over 512 + fold of previous layer's GEMM4 split-K partials into
// the f32 residual stream (nz=0 for layer 0, nz=3 after).
// ---------------------------------------------------------------------------
__global__ __launch_bounds__(256) void ln_kernel(
  float* __restrict__ h, const float* __restrict__ pz, int nz,
  const float* __restrict__ g, const float* __restrict__ bta,
  u16* __restrict__ hn)
{
  int row = blockIdx.x;
  int t = threadIdx.x;
  float v0 = h[row*512 + t], v1 = h[row*512 + 256 + t];
  for(int z=0; z<nz; z++){
    v0 += pz[(size_t)z*524288 + row*512 + t];
    v1 += pz[(size_t)z*524288 + row*512 + 256 + t];
  }
  if(nz){ h[row*512+t] = v0; h[row*512+256+t] = v1; }
  float s = v0+v1, s2 = v0*v0 + v1*v1;
#pragma unroll
  for(int off=32; off; off>>=1){ s += __shfl_down(s, off); s2 += __shfl_down(s2, off); }
  __shared__ float red[8];
  int wid = t>>6;
  if((t&63)==0){ red[wid*2]=s; red[wid*2+1]=s2; }
  __syncthreads();
  float mu = (red[0]+red[2]+red[4]+red[6]) * (1.f/512.f);
  float ms = (red[1]+red[3]+red[5]+red[7]) * (1.f/512.f);
  float rstd = rsqrtf(ms - mu*mu + 1e-5f);
  hn[row*512+t]     = f2bf((v0-mu)*rstd*g[t]     + bta[t]);
  hn[row*512+256+t] = f2bf((v1-mu)*rstd*g[t+256] + bta[t+256]);
}

// ---------------------------------------------------------------------------
// Sum GEMM2's 8 split-K partials -> s[b]=dot(Bm,Cm), dt as bf16.
// 8 lanes per row, 32 rows per block, grid 32.
// ---------------------------------------------------------------------------
__global__ __launch_bounds__(256) void sdt_kernel(
  const float* __restrict__ xp, u16* __restrict__ dtb, float* __restrict__ sb)
{
  int t = threadIdx.x;
  int row = blockIdx.x*32 + (t>>3);
  int sub = t&7;
  const float* xr = xp + row*96;
  float a = 0.f;
#pragma unroll
  for(int i=0;i<4;i++){
    int n = sub + 8*i;
    float Bn=0.f, Cn=0.f;
#pragma unroll
    for(int z=0;z<8;z++){ Bn += xr[(size_t)z*98304 + 32+n]; Cn += xr[(size_t)z*98304 + 64+n]; }
    a += Bn*Cn;
  }
  a += __shfl_xor(a,1); a += __shfl_xor(a,2); a += __shfl_xor(a,4);
  if(sub==0) sb[row] = a;
#pragma unroll
  for(int i=0;i<4;i++){
    int r = sub + 8*i;
    float d=0.f;
#pragma unroll
    for(int z=0;z<8;z++) d += xr[(size_t)z*98304 + r];
    dtb[row*32+r] = f2bf(d);
  }
}

// ---------------------------------------------------------------------------
// bf16 MFMA GEMM, register-prefetch pipelined K-loop (next tile's global
// loads issued before the MFMA block; vmcnt wait lands at next iter's
// ds_write, so load latency overlaps MFMA).
// C[m,n] = sum_k A[m,k]*B[n,k]   (B stored N x K)
// MODE 0: GEMM1 -> u = silu(xc*cw3+cb) [n<1536], zs = silu(z) [n>=1536]
// MODE 1: GEMM2 -> split-K partial store to o32 + z*98304 (1024x96 slices)
// MODE 2: GEMM3 -> delta=softplus(acc+bdt); y = u*(delta*s + Dp)*zs (bf16)
// MODE 3: GEMM4 -> split-K partial store to o32 + z*524288 (1024x512 slices)
// mfma_f32_16x16x32_bf16 layouts (learn_hip m89/m91/m97 verified):
//   A/B frag: lane holds [idx=lane&15][k=(lane>>4)*8+j]
//   C/D: col=lane&15, row=(lane>>4)*4+reg
// ---------------------------------------------------------------------------
template<int BM,int BN,int WM,int WN,int MODE>
__global__ __launch_bounds__(256)
void gemm_mfma(const u16* __restrict__ A, int lda,
               const u16* __restrict__ B, int ldb, int Klen,
               const float* __restrict__ p0, const float* __restrict__ p1,
               const float* __restrict__ p2,
               const u16* __restrict__ q0, const u16* __restrict__ q1,
               u16* __restrict__ o16a, u16* __restrict__ o16b,
               float* __restrict__ o32)
{
  constexpr int MI = WM/16, NI = WN/16;
  constexpr int WCOLS = BN/WN;
  constexpr int LDSK = 40;               // 32+8 pad: 2-way bank alias only (free)
  constexpr int CA = BM*4, CB = BN*4;    // 16B chunks per tile
  constexpr int IA = (CA+255)/256, IB = (CB+255)/256;
  static_assert((BM/WM)*(BN/WN) == 4, "4 waves");
  __shared__ u16 As[BM*LDSK];
  __shared__ u16 Bs[BN*LDSK];
  const int tid  = threadIdx.x;
  const int lane = tid & 63, wid = tid >> 6;
  const int wm = wid / WCOLS, wn = wid % WCOLS;
  const int m0 = blockIdx.y*BM, n0 = blockIdx.x*BN;
  const int k0 = blockIdx.z*Klen;
  const int qd = lane>>4, lr = lane&15;

  v4f acc[MI][NI];
#pragma unroll
  for(int i=0;i<MI;i++)
#pragma unroll
    for(int j=0;j<NI;j++) acc[i][j] = v4f{0.f,0.f,0.f,0.f};

  v8s ra[IA], rb[IB];
  auto loadAB = [&](int kk){
#pragma unroll
    for(int i=0;i<IA;i++){ int s = tid + i*256;
      if(CA%256==0 || s<CA){ int r=s>>2, kg=s&3;
        ra[i] = *(const v8s*)(A + (size_t)(m0+r)*lda + (k0+kk) + kg*8); } }
#pragma unroll
    for(int i=0;i<IB;i++){ int s = tid + i*256;
      if(CB%256==0 || s<CB){ int r=s>>2, kg=s&3;
        rb[i] = *(const v8s*)(B + (size_t)(n0+r)*ldb + (k0+kk) + kg*8); } }
  };

  loadAB(0);
  for(int kk=0; kk<Klen; kk+=32){
    __syncthreads();
#pragma unroll
    for(int i=0;i<IA;i++){ int s = tid + i*256;
      if(CA%256==0 || s<CA){ int r=s>>2, kg=s&3;
        *(v8s*)(As + r*LDSK + kg*8) = ra[i]; } }
#pragma unroll
    for(int i=0;i<IB;i++){ int s = tid + i*256;
      if(CB%256==0 || s<CB){ int r=s>>2, kg=s&3;
        *(v8s*)(Bs + r*LDSK + kg*8) = rb[i]; } }
    __syncthreads();
    if(kk+32 < Klen) loadAB(kk+32);     // in-flight during MFMA below
    v8s af[MI], bfv[NI];
#pragma unroll
    for(int i=0;i<MI;i++) af[i]  = *(const v8s*)(As + (wm*WM + i*16 + lr)*LDSK + qd*8);
#pragma unroll
    for(int j=0;j<NI;j++) bfv[j] = *(const v8s*)(Bs + (wn*WN + j*16 + lr)*LDSK + qd*8);
#pragma unroll
    for(int i=0;i<MI;i++)
#pragma unroll
      for(int j=0;j<NI;j++)
        acc[i][j] = __builtin_amdgcn_mfma_f32_16x16x32_bf16(af[i], bfv[j], acc[i][j], 0,0,0);
  }

#pragma unroll
  for(int i=0;i<MI;i++)
#pragma unroll
    for(int j=0;j<NI;j++){
      const int gb0 = m0 + wm*WM + i*16 + qd*4;
      const int ge  = n0 + wn*WN + j*16 + lr;
#pragma unroll
      for(int r=0;r<4;r++){
        const int gb = gb0 + r;
        float val = acc[i][j][r];
        if constexpr (MODE==0){
          if(ge < 1536){
            float t = val * p0[ge*4+3] + p1[ge];      // conv last tap + bias
            o16a[(size_t)gb*1536 + ge] = f2bf(siluf(t));
          } else {
            o16b[(size_t)gb*1536 + (ge-1536)] = f2bf(siluf(val));
          }
        } else if constexpr (MODE==1){
          o32[(size_t)blockIdx.z*98304 + (size_t)gb*96 + ge] = val;
        } else if constexpr (MODE==2){
          float delta = softplusf(val + p0[ge]);
          float uu = bf2f(q0[(size_t)gb*1536+ge]);
          float zz = bf2f(q1[(size_t)gb*1536+ge]);
          o16a[(size_t)gb*1536+ge] = f2bf(uu*(delta*p2[gb] + p1[ge])*zz);
        } else {
          o32[(size_t)blockIdx.z*524288 + (size_t)gb*512 + ge] = val;
        }
      }
    }
}

// ---------------------------------------------------------------------------
// Head: folds layer-3 GEMM4 partials, then lg/gate/MLP/sigmoid. Block per row.
// ---------------------------------------------------------------------------
__global__ __launch_bounds__(256) void head_kernel(
  const float* __restrict__ x, const float* __restrict__ h,
  const float* __restrict__ pz,
  const float* __restrict__ wlog, const float* __restrict__ blog,
  const float* __restrict__ wg, const float* __restrict__ bg,
  const float* __restrict__ wh1, const float* __restrict__ bh1,
  const float* __restrict__ wh2, const float* __restrict__ bh2,
  float* __restrict__ out)
{
  int b = blockIdx.x, t = threadIdx.x;
  __shared__ float fused[512];
  __shared__ float part[256];
  __shared__ float z1s[32];
  float lgin = x[b*68+0]*wlog[0] + x[b*68+1]*wlog[1]
             + x[b*68+2]*wlog[2] + x[b*68+3]*wlog[3] + blog[0];
  float lg = 1.f/(1.f+__expf(-lgin));
  for(int d=t; d<512; d+=256){
    float m = h[(size_t)b*512+d]
            + pz[(size_t)0*524288 + b*512 + d]
            + pz[(size_t)1*524288 + b*512 + d]
            + pz[(size_t)2*524288 + b*512 + d];
    fused[d] = m*(lg*wg[d] + bg[d]);
  }
  __syncthreads();
  int j = t&31, c = t>>5;
  float p = 0.f;
#pragma unroll
  for(int i=0;i<64;i++){ int d = c*64+i; p += fused[d]*wh1[j*512+d]; }
  part[t] = p;
  __syncthreads();
  if(t < 32){
    float z = bh1[t];
#pragma unroll
    for(int cc=0; cc<8; cc++) z += part[cc*32+t];
    z1s[t] = fmaxf(z, 0.f);
  }
  __syncthreads();
  if(t==0){
    float lo = bh2[0];
#pragma unroll
    for(int jj=0;jj<32;jj++) lo += z1s[jj]*wh2[jj];
    out[b] = 1.f/(1.f+__expf(-lo));
  }
}

// ---------------------------------------------------------------------------
extern "C" void kernel_launch(void* const* d_in, const int* in_sizes, int n_in,
                              void* d_out, int out_size, void* d_ws, size_t ws_size,
                              hipStream_t stream)
{
  const float* x        = (const float*)d_in[0];
  const float* w_in     = (const float*)d_in[1];
  const float* b_in     = (const float*)d_in[2];
  const float* ln_g     = (const float*)d_in[3];
  const float* ln_b     = (const float*)d_in[4];
  const float* W_inproj = (const float*)d_in[5];
  const float* conv_w   = (const float*)d_in[6];
  const float* conv_b   = (const float*)d_in[7];
  const float* W_xproj  = (const float*)d_in[8];
  // d_in[9] W_dt, d_in[10] b_dt
  const float* W_dt     = (const float*)d_in[9];
  const float* b_dt     = (const float*)d_in[10];
  // d_in[11] A_log: dead — scan is a single step from h0=0, dA only scales h0
  const float* D_skip   = (const float*)d_in[12];
  const float* W_outproj= (const float*)d_in[13];
  const float* w_log    = (const float*)d_in[14];
  const float* b_log    = (const float*)d_in[15];
  const float* W_gate   = (const float*)d_in[16];
  const float* b_gate   = (const float*)d_in[17];
  const float* W_h1     = (const float*)d_in[18];
  const float* b_h1     = (const float*)d_in[19];
  const float* W_h2     = (const float*)d_in[20];
  const float* b_h2     = (const float*)d_in[21];
  float* out = (float*)d_out;
  (void)in_sizes; (void)n_in; (void)out_size; (void)ws_size;

  char* ws = (char*)d_ws;
  size_t off = 0;
  auto alloc = [&](size_t bytes)->char*{
    char* p = ws + off; off = (off + bytes + 255) & ~(size_t)255; return p; };
  u16*   wInB  = (u16*)  alloc(6291456u*2);   // 4 x 3072 x 512
  u16*   wXB   = (u16*)  alloc(589824u*2);    // 4 x 96 x 1536
  u16*   wDtB  = (u16*)  alloc(196608u*2);    // 4 x 1536 x 32
  u16*   wOutB = (u16*)  alloc(3145728u*2);   // 4 x 512 x 1536
  float* h     = (float*)alloc(524288u*4);    // 1024 x 512 residual (f32)
  u16*   hn    = (u16*)  alloc(524288u*2);    // layernormed, bf16
  u16*   u     = (u16*)  alloc(1572864u*2);   // 1024 x 1536
  u16*   zs    = (u16*)  alloc(1572864u*2);   // silu(z)
  float* xpart = (float*)alloc(8u*98304u*4);  // GEMM2 split-K partials
  u16*   dtb   = (u16*)  alloc(32768u*2);     // 1024 x 32
  float* sb    = (float*)alloc(1024u*4);      // s[b]
  u16*   y     = (u16*)  alloc(1572864u*2);   // 1024 x 1536
  float* hpart = (float*)alloc(3u*524288u*4); // GEMM4 split-K partials

  cvt_kernel<<<9984,256,0,stream>>>(W_inproj, W_xproj, W_dt, W_outproj,
                                    wInB, wXB, wDtB, wOutB);
  input_kernel<<<2048,256,0,stream>>>(x, w_in, b_in, h);

  for(int l=0;l<4;l++){
    ln_kernel<<<1024,256,0,stream>>>(h, hpart, l?3:0, ln_g+l*512, ln_b+l*512, hn);
    // GEMM1: hn(1024x512) @ W_inproj^T -> u | zs   (N=3072, K=512), 768 blocks
    gemm_mfma<64,64,32,32,0><<<dim3(48,16,1),256,0,stream>>>(
      hn, 512, wInB+(size_t)l*1572864, 512, 512,
      conv_w+l*6144, conv_b+l*1536, nullptr, nullptr, nullptr, u, zs, nullptr);
    // GEMM2: u(1024x1536) @ W_xproj^T -> xpart (N=96), split-K=8, no atomics
    gemm_mfma<64,96,32,48,1><<<dim3(1,16,8),256,0,stream>>>(
      u, 1536, wXB+(size_t)l*147456, 1536, 192,
      nullptr, nullptr, nullptr, nullptr, nullptr, nullptr, nullptr, xpart);
    sdt_kernel<<<32,256,0,stream>>>(xpart, dtb, sb);
    // GEMM3: dt(1024x32) @ W_dt^T -> delta -> y   (N=1536, K=32)
    gemm_mfma<64,64,32,32,2><<<dim3(24,16,1),256,0,stream>>>(
      dtb, 32, wDtB+(size_t)l*49152, 32, 32,
      b_dt+l*1536, D_skip+l*1536, sb, u, zs, y, nullptr, nullptr);
    // GEMM4: y(1024x1536) @ W_outproj^T -> hpart (N=512), split-K=3, 384 blocks
    gemm_mfma<64,64,32,32,3><<<dim3(8,16,3),256,0,stream>>>(
      y, 1536, wOutB+(size_t)l*786432, 1536, 512,
      nullptr, nullptr, nullptr, nullptr, nullptr, nullptr, nullptr, hpart);
  }

  head_kernel<<<1024,256,0,stream>>>(x, h, hpart, w_log, b_log, W_gate, b_gate,
                                     W_h1, b_h1, W_h2, b_h2, out);
}